// Round 5
// baseline (19152.406 us; speedup 1.0000x reference)
//
#include <hip/hip_runtime.h>

#define NN 50000
#define NE 800000

__device__ __forceinline__ float siluf(float x){ return x/(1.0f+__expf(-x)); }
__device__ __forceinline__ float sigmf(float x){ return 1.0f/(1.0f+__expf(-x)); }

#define C_S 0.3826834323650898f
#define C_X 0.9238795325112867f
#define RS16 0.25f                  // 1/sqrt(16)
#define RS32 0.1767766952966369f    // 1/sqrt(32)
#define RS48 0.14433756729740643f   // 1/sqrt(48)
#define RS10 0.31622776601683794f   // 1/sqrt(10)
#define SR2  0.1f                   // 1/sqrt(100)
#define ISQ3 0.5773502691896258f
#define SQ3F 1.7320508075688772f
#define ISNN 0.25f                  // 1/sqrt(16)
#define EMBS 2.8234621965789103f    // sqrt(10)/1.12
#define PIF  3.14159265358979323846f

// ---------------------------------------------------------------- embed (wave per node)
__global__ void k_embed(const float* __restrict__ oh, const float* __restrict__ W,
                        const float* __restrict__ b, float* __restrict__ xs)
{
    __shared__ float lw[118*16];
    __shared__ float lb[16];
    for (int i = threadIdx.x; i < 118*16; i += blockDim.x) lw[i] = W[i];
    if (threadIdx.x < 16) lb[threadIdx.x] = b[threadIdx.x];
    __syncthreads();
    int gw = (blockIdx.x*blockDim.x + threadIdx.x) >> 6;   // global wave = node
    int lane = threadIdx.x & 63;
    if (gw >= NN) return;
    float acc[16];
#pragma unroll
    for (int j = 0; j < 16; ++j) acc[j] = 0.f;
    for (int i = lane; i < 118; i += 64) {                 // coalesced
        float o = oh[(size_t)gw*118 + i];
#pragma unroll
        for (int j = 0; j < 16; ++j) acc[j] += o*lw[i*16 + j];
    }
#pragma unroll
    for (int d = 32; d; d >>= 1) {
#pragma unroll
        for (int j = 0; j < 16; ++j) acc[j] += __shfl_xor(acc[j], d, 64);
    }
    if (lane == 0) {
        float4 f0 = {acc[0]+lb[0],  acc[1]+lb[1],  acc[2]+lb[2],  acc[3]+lb[3]};
        float4 f1 = {acc[4]+lb[4],  acc[5]+lb[5],  acc[6]+lb[6],  acc[7]+lb[7]};
        float4 f2 = {acc[8]+lb[8],  acc[9]+lb[9],  acc[10]+lb[10],acc[11]+lb[11]};
        float4 f3 = {acc[12]+lb[12],acc[13]+lb[13],acc[14]+lb[14],acc[15]+lb[15]};
        float* o = xs + (size_t)gw*48;
        *(float4*)(o+0) = f0; *(float4*)(o+4) = f1;
        *(float4*)(o+8) = f2; *(float4*)(o+12) = f3;
    }
}

// ---------------------------------------------------------------- sort build
__global__ void k_hist(const int* __restrict__ dstv, int* __restrict__ cursor)
{
    int e = blockIdx.x*blockDim.x + threadIdx.x;
    if (e < NE) atomicAdd(&cursor[dstv[e]], 1);
}

__global__ void k_scan(int* __restrict__ cnt, int* __restrict__ start)
{
    __shared__ int part[1024];
    const int L = (NN + 1023)/1024;
    int t = threadIdx.x;
    int b0 = t*L, b1 = b0 + L; if (b1 > NN) b1 = NN; if (b0 > NN) b0 = NN;
    int s = 0;
    for (int i = b0; i < b1; ++i) s += cnt[i];
    part[t] = s;
    __syncthreads();
    for (int off = 1; off < 1024; off <<= 1) {
        int vv = (t >= off) ? part[t-off] : 0;
        __syncthreads();
        part[t] += vv;
        __syncthreads();
    }
    int run = (t == 0) ? 0 : part[t-1];
    for (int i = b0; i < b1; ++i) {
        int cc = cnt[i];
        start[i] = run;
        cnt[i] = run;
        run += cc;
    }
    if (t == 1023) start[NN] = part[1023];
}

__global__ void k_scatter(const int* __restrict__ dstv, int* __restrict__ cursor,
                          int* __restrict__ perm)
{
    int e = blockIdx.x*blockDim.x + threadIdx.x;
    if (e < NE) {
        int p = atomicAdd(&cursor[dstv[e]], 1);
        perm[p] = e;
    }
}

// ---------------------------------------------------------------- R2 panel transpose
// R2T[(j/4)][k][j%4] — each output-column group's 100x4 weight panel contiguous
__global__ void k_r2t(const float* __restrict__ R2, float* __restrict__ R2T, int wout)
{
    int idx = blockIdx.x*blockDim.x + threadIdx.x;
    if (idx >= 100*wout) return;
    int k = idx / wout, j = idx - k*wout;
    R2T[(size_t)(j>>2)*400 + k*4 + (j&3)] = R2[idx];
}

// ---------------------------------------------------------------- node pre-linear
template<int SIN, int SOUT, int V>
__global__ void k_pre(const float* __restrict__ xs, const float* __restrict__ xv,
                      const float* __restrict__ Ws, const float* __restrict__ Wv,
                      float* __restrict__ xs1, float* __restrict__ xv1,
                      float ss, float sv)
{
    __shared__ float lws[SIN*SOUT];
    __shared__ float lwv[(V > 0) ? 256 : 1];
    for (int i = threadIdx.x; i < SIN*SOUT; i += blockDim.x) lws[i] = Ws[i];
    if constexpr (V > 0)
        for (int i = threadIdx.x; i < 256; i += blockDim.x) lwv[i] = Wv[i];
    __syncthreads();
    int n = blockIdx.x*blockDim.x + threadIdx.x;
    if (n >= NN) return;
    float xr[SIN];
#pragma unroll
    for (int u = 0; u < SIN; ++u) xr[u] = xs[n*48 + u];
#pragma unroll
    for (int j = 0; j < SOUT; ++j) {
        float a = 0.f;
#pragma unroll
        for (int u = 0; u < SIN; ++u) a += xr[u]*lws[u*SOUT + j];
        xs1[n*SOUT + j] = a*ss;
    }
    if constexpr (V > 0) {
        float vr[48];
#pragma unroll
        for (int i = 0; i < 48; ++i) vr[i] = xv[n*48 + i];
#pragma unroll
        for (int w = 0; w < 16; ++w) {
            float a0 = 0.f, a1 = 0.f, a2 = 0.f;
#pragma unroll
            for (int v = 0; v < 16; ++v) {
                float wt = lwv[v*16 + w];
                a0 += vr[v*3+0]*wt; a1 += vr[v*3+1]*wt; a2 += vr[v*3+2]*wt;
            }
            xv1[n*48 + w*3 + 0] = a0*sv;
            xv1[n*48 + w*3 + 1] = a1*sv;
            xv1[n*48 + w*3 + 2] = a2*sv;
        }
    }
}

// ---------------------------------------------------------------- edge kernel v4
// 1 thread/edge, 512-thread blocks. R2 panels staged in LDS in CW-output
// chunks; dot reads are wave-uniform broadcasts (conflict-free, minimal BW).
// h[100] in regs across chunks. 16 waves/CU (VGPR<=128, 2 blocks/CU).
template<int S,int V,int WOUT,int CW,int NCH,bool VEC_OUT,bool FOLD,int WM,int WMS>
__global__ void __launch_bounds__(512,4) k_edge4(
    const float* __restrict__ pos, const float* __restrict__ ea,
    const int* __restrict__ srcv, const int* __restrict__ dstv,
    const int* __restrict__ perm,
    const float* __restrict__ xs1, const float* __restrict__ xv1,
    const float* __restrict__ R1, const float* __restrict__ R2T,
    const float* __restrict__ WF, float* __restrict__ msg, int p0, int p1)
{
    constexpr int O1 = 4*S;
    constexpr int O2 = VEC_OUT ? O1 + S : O1;
    constexpr int O3 = (VEC_OUT && V > 0) ? O2 + 4*V : O2;
    constexpr int NF = FOLD ? (S+V)*8 : 1;
    __shared__ __align__(16) float lR1[1200];
    __shared__ __align__(16) float lR2[100*CW];
    __shared__ float lWF[NF];
    const int tid = threadIdx.x;
    for (int idx = tid; idx < 1000; idx += 512) {
        int i = idx/100, k = idx%100;
        lR1[k*12 + i] = R1[idx];                // transposed [k][i]
    }
    if constexpr (FOLD)
        for (int i = tid; i < NF; i += 512) lWF[i] = WF[i];

    const int p = p0 + blockIdx.x*512 + tid;
    const bool valid = (p < p1);
    const int pc = valid ? p : (p1 - 1);
    const int e = perm[pc];
    const int src = srcv[e];
    const int dst = dstv[e];
    float es0, es1, es2, es3, ev0, ev1, ev2;
    float eb[10];
    {
        float vx = pos[3*src+0] - pos[3*dst+0];
        float vy = pos[3*src+1] - pos[3*dst+1];
        float vz = pos[3*src+2] - pos[3*dst+2];
        float r  = sqrtf(vx*vx + vy*vy + vz*vz + 1e-12f);
        float ir = 1.0f/r;
        float uu = 2.0f*(r*(1.0f/3.5f) - 1.0f);
        float cut = (uu > 0.0f) ? 0.0f
                  : ((uu < -1.0f) ? 1.0f : 0.5f*(1.0f - cosf(PIF*uu)));
        es0 = ea[3*e+0]; es1 = ea[3*e+1]; es2 = ea[3*e+2]; es3 = cut;
        float cs = cut*SQ3F*ir;
        ev0 = cs*vx; ev1 = cs*vy; ev2 = cs*vz;
        float q = r*2.5714285714285716f;        // r/step, step = 3.5/9
#pragma unroll
        for (int i = 0; i < 10; ++i) {
            float t = q - (float)i;
            eb[i] = __expf(-t*t)*EMBS;
        }
    }
    __syncthreads();                            // lR1, lWF ready
    float h[100];
#pragma unroll
    for (int k = 0; k < 100; ++k) {
        const float4 w0 = *(const float4*)&lR1[k*12];
        const float4 w1 = *(const float4*)&lR1[k*12 + 4];
        const float2 w2 = *(const float2*)&lR1[k*12 + 8];
        float a = eb[0]*w0.x + eb[1]*w0.y + eb[2]*w0.z + eb[3]*w0.w
                + eb[4]*w1.x + eb[5]*w1.y + eb[6]*w1.z + eb[7]*w1.w
                + eb[8]*w2.x + eb[9]*w2.y;
        h[k] = siluf(a*RS10);
    }
    const float* xsrow = xs1 + (size_t)src*S;
    const float* xvrow = xv1 + (size_t)src*48;
    float* msgrow = msg + (size_t)(p - p0)*WM;
    float fold8[8];
    if constexpr (FOLD) {
#pragma unroll
        for (int j = 0; j < 8; ++j) fold8[j] = 0.f;
    }

#pragma unroll 1
    for (int ch = 0; ch < NCH; ++ch) {
        const int g0 = ch*(CW/4);
        __syncthreads();                        // previous chunk consumed
        {
            const float4* sp = (const float4*)(R2T + (size_t)g0*400);
            float4* dp = (float4*)lR2;
            for (int idx = tid; idx < 25*CW; idx += 512) dp[idx] = sp[idx];
        }
        __syncthreads();
#pragma unroll 1
        for (int g = 0; g < CW/4; ++g) {
            const int j0 = 4*(g0 + g);
            // ---- issue operand gathers (consumed after the dot)
            float4 LA = {0,0,0,0}, LB = {0,0,0,0}, LC = {0,0,0,0};
            if (j0 < O1)                            { LA.x = xsrow[j0 >> 2]; }
            else if (VEC_OUT && j0 < O2)            { LA = *(const float4*)(xsrow + (j0 - O1)); }
            else if (VEC_OUT && V > 0 && j0 < O3) {
                int u2 = (j0 - O2) >> 2;
                LA.x = xvrow[u2*3]; LA.y = xvrow[u2*3+1]; LA.z = xvrow[u2*3+2];
            } else if (V > 0) {
                const float4* pv = (const float4*)(xvrow + (j0 - O3)*3);
                LA = pv[0]; LB = pv[1]; LC = pv[2];
            }
            // ---- dot: broadcast LDS reads (wave-uniform address)
            const float* wp = lR2 + g*400;
            float a0=0.f, a1=0.f, a2=0.f, a3=0.f;
#pragma unroll
            for (int k = 0; k < 100; ++k) {
                const float4 w = *(const float4*)(wp + 4*k);
                float hk = h[k];
                a0 = fmaf(hk, w.x, a0);
                a1 = fmaf(hk, w.y, a1);
                a2 = fmaf(hk, w.z, a2);
                a3 = fmaf(hk, w.w, a3);
            }
            a0 *= SR2; a1 *= SR2; a2 *= SR2; a3 *= SR2;
            // ---- consume
            if (j0 < O1) {                                   // w1: scalar message
                int u = j0 >> 2;
                float dv = a0*es0 + a1*es1 + a2*es2 + a3*es3;
                float v = 0.5f*LA.x*dv;
                if constexpr (FOLD) {
#pragma unroll
                    for (int j = 0; j < 8; ++j) fold8[j] = fmaf(v, lWF[u*8 + j], fold8[j]);
                } else {
                    if (valid) msgrow[u] = v;
                }
            } else if (VEC_OUT && j0 < O2) {                 // w2: s->v raw (12 floats)
                int u0 = j0 - O1;
                float m0 = LA.x*a0, m1 = LA.y*a1, m2 = LA.z*a2, m3 = LA.w*a3;
                if (valid) {
                    msgrow[WMS+(u0+0)*3+0] = m0*ev0; msgrow[WMS+(u0+0)*3+1] = m0*ev1; msgrow[WMS+(u0+0)*3+2] = m0*ev2;
                    msgrow[WMS+(u0+1)*3+0] = m1*ev0; msgrow[WMS+(u0+1)*3+1] = m1*ev1; msgrow[WMS+(u0+1)*3+2] = m1*ev2;
                    msgrow[WMS+(u0+2)*3+0] = m2*ev0; msgrow[WMS+(u0+2)*3+1] = m2*ev1; msgrow[WMS+(u0+2)*3+2] = m2*ev2;
                    msgrow[WMS+(u0+3)*3+0] = m3*ev0; msgrow[WMS+(u0+3)*3+1] = m3*ev1; msgrow[WMS+(u0+3)*3+2] = m3*ev2;
                }
            } else if (VEC_OUT && V > 0 && j0 < O3) {        // w3: v->v raw (3 floats)
                int u2 = (j0 - O2) >> 2;
                float dv = 0.5f*(a0*es0 + a1*es1 + a2*es2 + a3*es3);
                if (valid) {
                    msgrow[WMS+(S+u2)*3+0] = dv*LA.x;
                    msgrow[WMS+(S+u2)*3+1] = dv*LA.y;
                    msgrow[WMS+(S+u2)*3+2] = dv*LA.z;
                }
            } else if (V > 0) {                              // w4: v->s
                int u0 = j0 - O3;
                float d0 = LA.x*ev0 + LA.y*ev1 + LA.z*ev2;
                float d1 = LA.w*ev0 + LB.x*ev1 + LB.y*ev2;
                float d2 = LB.z*ev0 + LB.w*ev1 + LC.x*ev2;
                float d3 = LC.y*ev0 + LC.z*ev1 + LC.w*ev2;
                float v0 = a0*d0*ISQ3, v1 = a1*d1*ISQ3, v2 = a2*d2*ISQ3, v3 = a3*d3*ISQ3;
                if constexpr (FOLD) {
#pragma unroll
                    for (int j = 0; j < 8; ++j)
                        fold8[j] += v0*lWF[(S+u0+0)*8+j] + v1*lWF[(S+u0+1)*8+j]
                                  + v2*lWF[(S+u0+2)*8+j] + v3*lWF[(S+u0+3)*8+j];
                } else {
                    if (valid) {
                        msgrow[S+u0+0] = v0; msgrow[S+u0+1] = v1;
                        msgrow[S+u0+2] = v2; msgrow[S+u0+3] = v3;
                    }
                }
            }
        }
    }
    if constexpr (FOLD) {
        if (valid) {
            float4 f0 = {fold8[0], fold8[1], fold8[2], fold8[3]};
            float4 f1 = {fold8[4], fold8[5], fold8[6], fold8[7]};
            *(float4*)(msgrow + 0) = f0;
            *(float4*)(msgrow + 4) = f1;
        }
    }
}

// ---------------------------------------------------------------- segmented sum
template<int W>
__global__ void k_segsum(const float* __restrict__ msg, float* __restrict__ Y,
                         const int* __restrict__ start, int p0, int p1, int first)
{
    int idx = blockIdx.x*blockDim.x + threadIdx.x;
    if (idx >= NN*W) return;
    int n = idx / W;
    int c = idx - n*W;
    int lo = start[n], hi = start[n+1];
    if (lo < p0) lo = p0;
    if (hi > p1) hi = p1;
    float s = 0.f;
    if (lo < hi) {
        const float* q = msg + (size_t)(lo - p0)*W + c;
        for (int p = lo; p < hi; ++p) { s += *q; q += W; }
    }
    if (first) Y[idx] = s;
    else if (lo < hi) Y[idx] += s;
}

// ---------------------------------------------------------------- node post + gate (in-place)
// Y row: [YSW scalar | M*3 raw vec (m-major)]; applies lin2_v here.
template<int SIN, int YSW, int M, int WST, bool HASV>
__global__ void k_post(float* __restrict__ xsv, float* __restrict__ xvv,
                       const float* __restrict__ Y,
                       const float* __restrict__ scs, const float* __restrict__ scv,
                       const float* __restrict__ l2s, const float* __restrict__ l2v,
                       float s_sc, float s_l2s, float s_scv, float s_l2v)
{
    __shared__ float Lscs[SIN*48];
    __shared__ float Ll2s[YSW*48];
    __shared__ float Lscv[HASV ? 256 : 1];
    __shared__ float Ll2v[M*16];
    for (int i = threadIdx.x; i < SIN*48; i += blockDim.x) Lscs[i] = scs[i];
    for (int i = threadIdx.x; i < YSW*48; i += blockDim.x) Ll2s[i] = l2s[i];
    if constexpr (HASV)
        for (int i = threadIdx.x; i < 256; i += blockDim.x) Lscv[i] = scv[i];
    for (int i = threadIdx.x; i < M*16; i += blockDim.x) Ll2v[i] = l2v[i];
    __syncthreads();
    int n = blockIdx.x*blockDim.x + threadIdx.x;
    if (n >= NN) return;
    const float* yrow = Y + (size_t)n*WST;
    float xr[SIN];
#pragma unroll
    for (int u = 0; u < SIN; ++u) xr[u] = xsv[n*48 + u];
    float yr[YSW];
#pragma unroll
    for (int t = 0; t < YSW; ++t) yr[t] = yrow[t]*ISNN;
    float os[48];
    const float A = C_S*s_sc, B = C_X*s_l2s;
#pragma unroll
    for (int j = 0; j < 48; ++j) {
        float a = 0.f, b = 0.f;
#pragma unroll
        for (int u = 0; u < SIN; ++u) a += xr[u]*Lscs[u*48 + j];
#pragma unroll
        for (int t = 0; t < YSW; ++t) b += yr[t]*Ll2s[t*48 + j];
        os[j] = A*a + B*b;
    }
#pragma unroll
    for (int u = 0; u < 32; ++u) xsv[n*48 + u] = siluf(os[u]);
    float gg[16];
#pragma unroll
    for (int t = 0; t < 16; ++t) gg[t] = sigmf(os[32 + t]);
    // project raw vec messages: a_c[w] = sum_m yv[m][c] * l2v[m][w]
    float a0[16], a1[16], a2[16];
#pragma unroll
    for (int w = 0; w < 16; ++w) { a0[w]=0.f; a1[w]=0.f; a2[w]=0.f; }
#pragma unroll
    for (int m = 0; m < M; ++m) {
        float y0 = yrow[YSW + m*3 + 0];
        float y1 = yrow[YSW + m*3 + 1];
        float y2 = yrow[YSW + m*3 + 2];
#pragma unroll
        for (int w = 0; w < 16; ++w) {
            float wt = Ll2v[m*16 + w];
            a0[w] += y0*wt; a1[w] += y1*wt; a2[w] += y2*wt;
        }
    }
    const float Bv = ISNN*s_l2v*(HASV ? C_X : 1.0f);
    if constexpr (HASV) {
        float vr[48];
#pragma unroll
        for (int i = 0; i < 48; ++i) vr[i] = xvv[n*48 + i];
        const float Av = C_S*s_scv;
#pragma unroll
        for (int w = 0; w < 16; ++w) {
            float s0 = 0.f, s1 = 0.f, s2 = 0.f;
#pragma unroll
            for (int v = 0; v < 16; ++v) {
                float wt = Lscv[v*16 + w];
                s0 += vr[v*3+0]*wt; s1 += vr[v*3+1]*wt; s2 += vr[v*3+2]*wt;
            }
            xvv[n*48 + w*3 + 0] = (Av*s0 + Bv*a0[w])*gg[w];
            xvv[n*48 + w*3 + 1] = (Av*s1 + Bv*a1[w])*gg[w];
            xvv[n*48 + w*3 + 2] = (Av*s2 + Bv*a2[w])*gg[w];
        }
    } else {
#pragma unroll
        for (int w = 0; w < 16; ++w) {
            xvv[n*48 + w*3 + 0] = Bv*a0[w]*gg[w];
            xvv[n*48 + w*3 + 1] = Bv*a1[w]*gg[w];
            xvv[n*48 + w*3 + 2] = Bv*a2[w]*gg[w];
        }
    }
}

// ---------------------------------------------------------------- layer4 post + head
__global__ void k_final(const float* __restrict__ xsv, const float* __restrict__ Y8,
                        const float* __restrict__ scs,
                        const float* __restrict__ Wh, const float* __restrict__ bh,
                        float* __restrict__ out)
{
    __shared__ float Lscs[32*8];
    __shared__ float Lwh[24];
    __shared__ float Lbh[3];
    for (int i = threadIdx.x; i < 32*8; i += blockDim.x) Lscs[i] = scs[i];
    if (threadIdx.x < 24) Lwh[threadIdx.x] = Wh[threadIdx.x];
    if (threadIdx.x < 3)  Lbh[threadIdx.x] = bh[threadIdx.x];
    __syncthreads();
    int n = blockIdx.x*blockDim.x + threadIdx.x;
    if (n >= NN) return;
    float xr[32];
#pragma unroll
    for (int u = 0; u < 32; ++u) xr[u] = xsv[n*48 + u];
    const float CB = C_X*RS48*ISNN;
    float s8[8];
#pragma unroll
    for (int j = 0; j < 8; ++j) {
        float a = 0.f;
#pragma unroll
        for (int u = 0; u < 32; ++u) a += xr[u]*Lscs[u*8 + j];
        s8[j] = C_S*RS32*a + CB*Y8[n*8 + j];
    }
#pragma unroll
    for (int c = 0; c < 3; ++c) {
        float o = Lbh[c];
#pragma unroll
        for (int j = 0; j < 8; ++j) o += s8[j]*Lwh[j*3 + c];
        out[n*3 + c] = o;
    }
}

// ---------------------------------------------------------------- launcher
extern "C" void kernel_launch(void* const* d_in, const int* in_sizes, int n_in,
                              void* d_out, int out_size, void* d_ws, size_t ws_size,
                              hipStream_t stream)
{
    const float* pos       = (const float*)d_in[0];
    const float* onehot    = (const float*)d_in[1];
    const float* eattr     = (const float*)d_in[2];
    const float* W_embed   = (const float*)d_in[3];
    const float* b_embed   = (const float*)d_in[4];
    const float* l1_lin1_s = (const float*)d_in[5];
    const float* l1_sc_s   = (const float*)d_in[6];
    const float* l1_R1     = (const float*)d_in[7];
    const float* l1_R2     = (const float*)d_in[8];
    const float* l1_lin2_s = (const float*)d_in[9];
    const float* l1_lin2_v = (const float*)d_in[10];
    const float* l2_lin1_s = (const float*)d_in[11];
    const float* l2_lin1_v = (const float*)d_in[12];
    const float* l2_sc_s   = (const float*)d_in[13];
    const float* l2_sc_v   = (const float*)d_in[14];
    const float* l2_R1     = (const float*)d_in[15];
    const float* l2_R2     = (const float*)d_in[16];
    const float* l2_lin2_s = (const float*)d_in[17];
    const float* l2_lin2_v = (const float*)d_in[18];
    const float* l3_lin1_s = (const float*)d_in[19];
    const float* l3_lin1_v = (const float*)d_in[20];
    const float* l3_sc_s   = (const float*)d_in[21];
    const float* l3_sc_v   = (const float*)d_in[22];
    const float* l3_R1     = (const float*)d_in[23];
    const float* l3_R2     = (const float*)d_in[24];
    const float* l3_lin2_s = (const float*)d_in[25];
    const float* l3_lin2_v = (const float*)d_in[26];
    const float* l4_lin1_s = (const float*)d_in[27];
    const float* l4_lin1_v = (const float*)d_in[28];
    const float* l4_sc_s   = (const float*)d_in[29];
    const float* l4_R1     = (const float*)d_in[30];
    const float* l4_R2     = (const float*)d_in[31];
    const float* l4_lin2_s = (const float*)d_in[32];
    const float* W_head    = (const float*)d_in[33];
    const float* b_head    = (const float*)d_in[34];
    const int*   eidx      = (const int*)d_in[35];
    const int* srcv = eidx;
    const int* dstv = eidx + NE;

    float* ws = (float*)d_ws;
    size_t off = 0;
    float* XS    = ws + off; off += 48ull*NN;
    float* XV    = ws + off; off += 48ull*NN;
    float* XS1   = ws + off; off += 32ull*NN;
    float* XV1   = ws + off; off += 48ull*NN;
    float* Y     = ws + off; off += 192ull*NN;
    float* R2T   = ws + off; off += 24000;
    int*   start = (int*)(ws + off); off += NN + 1;
    int*   cursor= (int*)(ws + off); off += NN;
    int*   perm  = (int*)(ws + off); off += NE;
    float* MSG   = ws + off;
    size_t totalFloats = ws_size/4;
    size_t msgCap = (totalFloats > off) ? (totalFloats - off) : 0;

    dim3 th(256), be((NE + 255)/256), bn((NN + 255)/256);
    dim3 th5(512);

    // ---- build dst-sorted permutation (once)
    hipMemsetAsync(cursor, 0, NN*sizeof(int), stream);
    k_hist<<<be, th, 0, stream>>>(dstv, cursor);
    k_scan<<<1, 1024, 0, stream>>>(cursor, start);
    k_scatter<<<be, th, 0, stream>>>(dstv, cursor, perm);

    k_embed<<<(NN*64 + 255)/256, th, 0, stream>>>(onehot, W_embed, b_embed, XS);

    auto chunks = [&](int WM) {
        long ec = (WM > 0 && msgCap > 0) ? (long)(msgCap / (size_t)WM) : NE;
        ec &= ~511L;                     // multiple of 512 (edges per block)
        if (ec > NE) ec = NE;
        if (ec < 2048) ec = 2048;
        return ec;
    };

    // ---- layer 1 (S=16, V=0, WOUT=80, CW=80; msg width 64 = 16 scalar + 16*3 raw vec)
    {
        k_pre<16,16,0><<<bn, th, 0, stream>>>(XS, nullptr, l1_lin1_s, nullptr, XS1, XV1, RS16, RS16);
        k_r2t<<<(100*80 + 255)/256, th, 0, stream>>>(l1_R2, R2T, 80);
        long EC = chunks(64);
        for (long c0 = 0; c0 < NE; c0 += EC) {
            int p0 = (int)c0, p1 = (int)((c0 + EC < NE) ? c0 + EC : NE);
            dim3 ge(((p1-p0) + 511)/512);
            k_edge4<16,0,80,80,1,true,false,64,16><<<ge, th5, 0, stream>>>(
                pos, eattr, srcv, dstv, perm, XS1, XV1, l1_R1, R2T, nullptr, MSG, p0, p1);
            dim3 gs((NN*64 + 255)/256);
            k_segsum<64><<<gs, th, 0, stream>>>(MSG, Y, start, p0, p1, c0 == 0);
        }
        k_post<16,16,16,64,false><<<bn, th, 0, stream>>>(XS, XV, Y, l1_sc_s, nullptr,
                                                         l1_lin2_s, l1_lin2_v,
                                                         RS16, RS16, 0.f, RS16);
    }

    // ---- layers 2,3 (S=32, V=16, WOUT=240, CW=120; msg width 192 = 48 + 48*3)
    const float* L2w[2][6] = {
        {l2_lin1_s, l2_lin1_v, l2_R1, l2_R2, l2_lin2_v, l2_lin2_s},
        {l3_lin1_s, l3_lin1_v, l3_R1, l3_R2, l3_lin2_v, l3_lin2_s}};
    const float* L2sc[2][2] = {{l2_sc_s, l2_sc_v}, {l3_sc_s, l3_sc_v}};
    for (int L = 0; L < 2; ++L) {
        k_pre<32,32,16><<<bn, th, 0, stream>>>(XS, XV, L2w[L][0], L2w[L][1], XS1, XV1, RS32, RS16);
        k_r2t<<<(100*240 + 255)/256, th, 0, stream>>>(L2w[L][3], R2T, 240);
        long EC = chunks(192);
        for (long c0 = 0; c0 < NE; c0 += EC) {
            int p0 = (int)c0, p1 = (int)((c0 + EC < NE) ? c0 + EC : NE);
            dim3 ge(((p1-p0) + 511)/512);
            k_edge4<32,16,240,120,2,true,false,192,48><<<ge, th5, 0, stream>>>(
                pos, eattr, srcv, dstv, perm, XS1, XV1, L2w[L][2], R2T, nullptr, MSG, p0, p1);
            dim3 gs((NN*192 + 255)/256);
            k_segsum<192><<<gs, th, 0, stream>>>(MSG, Y, start, p0, p1, c0 == 0);
        }
        k_post<32,48,48,192,true><<<bn, th, 0, stream>>>(XS, XV, Y, L2sc[L][0], L2sc[L][1],
                                                         L2w[L][5], L2w[L][4],
                                                         RS32, RS48, RS16, RS48);
    }

    // ---- layer 4 (S=32, V=16, WOUT=144, CW=72; lin2_s folded -> msg width 8)
    {
        k_pre<32,32,16><<<bn, th, 0, stream>>>(XS, XV, l4_lin1_s, l4_lin1_v, XS1, XV1, RS32, RS16);
        k_r2t<<<(100*144 + 255)/256, th, 0, stream>>>(l4_R2, R2T, 144);
        long EC = chunks(8);
        for (long c0 = 0; c0 < NE; c0 += EC) {
            int p0 = (int)c0, p1 = (int)((c0 + EC < NE) ? c0 + EC : NE);
            dim3 ge(((p1-p0) + 511)/512);
            k_edge4<32,16,144,72,2,false,true,8,48><<<ge, th5, 0, stream>>>(
                pos, eattr, srcv, dstv, perm, XS1, XV1, l4_R1, R2T, l4_lin2_s, MSG, p0, p1);
            dim3 gs((NN*8 + 255)/256);
            k_segsum<8><<<gs, th, 0, stream>>>(MSG, Y, start, p0, p1, c0 == 0);
        }
        k_final<<<bn, th, 0, stream>>>(XS, Y, l4_sc_s, W_head, b_head, (float*)d_out);
    }
}

// Round 6
// 6124.555 us; speedup vs baseline: 3.1272x; 3.1272x over previous
//
#include <hip/hip_runtime.h>

#define NN 50000
#define NE 800000
#define TT 16384
#define RMAXT 6.0f
#define NBR 2048

__device__ __forceinline__ float siluf(float x){ return x/(1.0f+__expf(-x)); }
__device__ __forceinline__ float sigmf(float x){ return 1.0f/(1.0f+__expf(-x)); }

#define C_S 0.3826834323650898f
#define C_X 0.9238795325112867f
#define RS16 0.25f                  // 1/sqrt(16)
#define RS32 0.1767766952966369f    // 1/sqrt(32)
#define RS48 0.14433756729740643f   // 1/sqrt(48)
#define RS10 0.31622776601683794f   // 1/sqrt(10)
#define SR2  0.1f                   // 1/sqrt(100)
#define ISQ3 0.5773502691896258f
#define SQ3F 1.7320508075688772f
#define ISNN 0.25f                  // 1/sqrt(16)
#define EMBS 2.8234621965789103f    // sqrt(10)/1.12
#define PIF  3.14159265358979323846f

// ---------------------------------------------------------------- embed (wave per node)
__global__ void k_embed(const float* __restrict__ oh, const float* __restrict__ W,
                        const float* __restrict__ b, float* __restrict__ xs)
{
    __shared__ float lw[118*16];
    __shared__ float lb[16];
    for (int i = threadIdx.x; i < 118*16; i += blockDim.x) lw[i] = W[i];
    if (threadIdx.x < 16) lb[threadIdx.x] = b[threadIdx.x];
    __syncthreads();
    int gw = (blockIdx.x*blockDim.x + threadIdx.x) >> 6;
    int lane = threadIdx.x & 63;
    if (gw >= NN) return;
    float acc[16];
#pragma unroll
    for (int j = 0; j < 16; ++j) acc[j] = 0.f;
    for (int i = lane; i < 118; i += 64) {
        float o = oh[(size_t)gw*118 + i];
#pragma unroll
        for (int j = 0; j < 16; ++j) acc[j] += o*lw[i*16 + j];
    }
#pragma unroll
    for (int d = 32; d; d >>= 1) {
#pragma unroll
        for (int j = 0; j < 16; ++j) acc[j] += __shfl_xor(acc[j], d, 64);
    }
    if (lane == 0) {
        float* o = xs + (size_t)gw*48;
#pragma unroll
        for (int j = 0; j < 16; ++j) o[j] = acc[j] + lb[j];
    }
}

// ---------------------------------------------------------------- dst sort
__global__ void k_hist(const int* __restrict__ dstv, int* __restrict__ cursor)
{
    int e = blockIdx.x*blockDim.x + threadIdx.x;
    if (e < NE) atomicAdd(&cursor[dstv[e]], 1);
}

__global__ void k_scan(int* __restrict__ cnt, int* __restrict__ start)
{
    __shared__ int part[1024];
    const int L = (NN + 1023)/1024;
    int t = threadIdx.x;
    int b0 = t*L, b1 = b0 + L; if (b1 > NN) b1 = NN; if (b0 > NN) b0 = NN;
    int s = 0;
    for (int i = b0; i < b1; ++i) s += cnt[i];
    part[t] = s;
    __syncthreads();
    for (int off = 1; off < 1024; off <<= 1) {
        int vv = (t >= off) ? part[t-off] : 0;
        __syncthreads();
        part[t] += vv;
        __syncthreads();
    }
    int run = (t == 0) ? 0 : part[t-1];
    for (int i = b0; i < b1; ++i) {
        int cc = cnt[i];
        start[i] = run;
        cnt[i] = run;
        run += cc;
    }
    if (t == 1023) start[NN] = part[1023];
}

__global__ void k_scatter(const int* __restrict__ dstv, int* __restrict__ cursor,
                          int* __restrict__ perm, int* __restrict__ invd)
{
    int e = blockIdx.x*blockDim.x + threadIdx.x;
    if (e < NE) {
        int p = atomicAdd(&cursor[dstv[e]], 1);
        perm[p] = e;
        invd[e] = p;
    }
}

// ---------------------------------------------------------------- r sort (compound key: dst-chunk, r-bucket)
__global__ void k_histr(const float* __restrict__ pos, const int* __restrict__ srcv,
                        const int* __restrict__ dstv, const int* __restrict__ invd,
                        int* __restrict__ cnt, int ec)
{
    int e = blockIdx.x*blockDim.x + threadIdx.x;
    if (e >= NE) return;
    int s = srcv[e], d = dstv[e];
    float vx = pos[3*s+0]-pos[3*d+0], vy = pos[3*s+1]-pos[3*d+1], vz = pos[3*s+2]-pos[3*d+2];
    float r = sqrtf(vx*vx+vy*vy+vz*vz + 1e-12f);
    int rb = (int)(r*(NBR/RMAXT)); if (rb > NBR-1) rb = NBR-1;
    atomicAdd(&cnt[(invd[e]/ec)*NBR + rb], 1);
}

__global__ void k_scanN(int* __restrict__ cnt, int n)
{
    __shared__ int part[1024];
    const int L = (n + 1023)/1024;
    int t = threadIdx.x;
    int b0 = t*L, b1 = b0 + L; if (b1 > n) b1 = n; if (b0 > n) b0 = n;
    int s = 0;
    for (int i = b0; i < b1; ++i) s += cnt[i];
    part[t] = s;
    __syncthreads();
    for (int off = 1; off < 1024; off <<= 1) {
        int vv = (t >= off) ? part[t-off] : 0;
        __syncthreads();
        part[t] += vv;
        __syncthreads();
    }
    int run = (t == 0) ? 0 : part[t-1];
    for (int i = b0; i < b1; ++i) { int c = cnt[i]; cnt[i] = run; run += c; }
}

__global__ void k_scatr(const float* __restrict__ pos, const int* __restrict__ srcv,
                        const int* __restrict__ dstv, const int* __restrict__ invd,
                        int* __restrict__ cnt, int* __restrict__ permr, int ec)
{
    int e = blockIdx.x*blockDim.x + threadIdx.x;
    if (e >= NE) return;
    int s = srcv[e], d = dstv[e];
    float vx = pos[3*s+0]-pos[3*d+0], vy = pos[3*s+1]-pos[3*d+1], vz = pos[3*s+2]-pos[3*d+2];
    float r = sqrtf(vx*vx+vy*vy+vz*vz + 1e-12f);
    int rb = (int)(r*(NBR/RMAXT)); if (rb > NBR-1) rb = NBR-1;
    int pr = atomicAdd(&cnt[(invd[e]/ec)*NBR + rb], 1);
    permr[pr] = e;
}

// ---------------------------------------------------------------- filter table build
// TAB[t][g] = {w(t)[4g:4g+4], w(t+1)[4g:4g+4]}  (entry = 8 floats = 32B)
template<int WOUT>
__global__ void k_tab(const float* __restrict__ R1, const float* __restrict__ R2,
                      float* __restrict__ TAB)
{
    constexpr int NG = WOUT/4;
    __shared__ float lh[8*100];
    const int tid = threadIdx.x;
    const int t0 = blockIdx.x*8;
    for (int idx = tid; idx < 800; idx += 512) {
        int tl = idx/100, k = idx - tl*100;
        float r = (float)(t0+tl)*(RMAXT/(float)(TT-1));
        float q = r*2.5714285714285716f;
        float a = 0.f;
#pragma unroll
        for (int i = 0; i < 10; ++i) {
            float u = q - (float)i;
            a += __expf(-u*u)*EMBS*R1[i*100 + k];
        }
        lh[idx] = siluf(a*RS10);
    }
    __syncthreads();
    for (int idx = tid; idx < 8*NG; idx += 512) {
        int tl = idx/NG, j = idx - tl*NG;
        const float* hr = lh + tl*100;
        float a0=0.f, a1=0.f, a2=0.f, a3=0.f;
        for (int k = 0; k < 100; ++k) {
            float4 w = *(const float4*)(R2 + (size_t)k*WOUT + 4*j);
            float hk = hr[k];
            a0 = fmaf(hk, w.x, a0); a1 = fmaf(hk, w.y, a1);
            a2 = fmaf(hk, w.z, a2); a3 = fmaf(hk, w.w, a3);
        }
        a0 *= SR2; a1 *= SR2; a2 *= SR2; a3 *= SR2;
        int t = t0 + tl;
        float4 f = {a0, a1, a2, a3};
        *(float4*)(TAB + ((size_t)t*NG + j)*8) = f;
        if (t >= 1) *(float4*)(TAB + ((size_t)(t-1)*NG + j)*8 + 4) = f;
    }
}

// ---------------------------------------------------------------- node pre-linear
template<int SIN, int SOUT, int V>
__global__ void k_pre(const float* __restrict__ xs, const float* __restrict__ xv,
                      const float* __restrict__ Ws, const float* __restrict__ Wv,
                      float* __restrict__ xs1, float* __restrict__ xv1,
                      float ss, float sv)
{
    __shared__ float lws[SIN*SOUT];
    __shared__ float lwv[(V > 0) ? 256 : 1];
    for (int i = threadIdx.x; i < SIN*SOUT; i += blockDim.x) lws[i] = Ws[i];
    if constexpr (V > 0)
        for (int i = threadIdx.x; i < 256; i += blockDim.x) lwv[i] = Wv[i];
    __syncthreads();
    int n = blockIdx.x*blockDim.x + threadIdx.x;
    if (n >= NN) return;
    float xr[SIN];
#pragma unroll
    for (int u = 0; u < SIN; ++u) xr[u] = xs[n*48 + u];
#pragma unroll
    for (int j = 0; j < SOUT; ++j) {
        float a = 0.f;
#pragma unroll
        for (int u = 0; u < SIN; ++u) a += xr[u]*lws[u*SOUT + j];
        xs1[n*SOUT + j] = a*ss;
    }
    if constexpr (V > 0) {
        float vr[48];
#pragma unroll
        for (int i = 0; i < 48; ++i) vr[i] = xv[n*48 + i];
#pragma unroll
        for (int w = 0; w < 16; ++w) {
            float a0 = 0.f, a1 = 0.f, a2 = 0.f;
#pragma unroll
            for (int v = 0; v < 16; ++v) {
                float wt = lwv[v*16 + w];
                a0 += vr[v*3+0]*wt; a1 += vr[v*3+1]*wt; a2 += vr[v*3+2]*wt;
            }
            xv1[n*48 + w*3 + 0] = a0*sv;
            xv1[n*48 + w*3 + 1] = a1*sv;
            xv1[n*48 + w*3 + 2] = a2*sv;
        }
    }
}

// ---------------------------------------------------------------- edge kernel v5 (table lerp)
// 1 thread/edge, r-sorted processing order (table gathers near-broadcast),
// scatter row write to dst-sorted position invd[e]. lin2_v folded (W=96/64),
// lin2_s folded for layer 4 (W=8). No per-edge MLP.
template<int S,int V,int WOUT,bool VEC_OUT,bool FOLD,int WM,int WMS>
__global__ void __launch_bounds__(256) k_edge5(
    const float* __restrict__ pos, const float* __restrict__ ea,
    const int* __restrict__ srcv, const int* __restrict__ dstv,
    const int* __restrict__ permr, const int* __restrict__ invd,
    const float* __restrict__ xs1, const float* __restrict__ xv1,
    const float* __restrict__ TAB, const float* __restrict__ WF,
    float* __restrict__ msg, int p0, int p1)
{
    constexpr int O1 = 4*S;
    constexpr int O2 = VEC_OUT ? O1 + S : O1;
    constexpr int O3 = (VEC_OUT && V > 0) ? O2 + 4*V : O2;
    constexpr int NG = WOUT/4;
    constexpr int NF = FOLD ? (S+V)*8 : (VEC_OUT ? (S+V)*16 : 1);
    __shared__ float lWF[NF];
    if constexpr (NF > 1)
        for (int i = threadIdx.x; i < NF; i += 256) lWF[i] = WF[i];

    const int p = p0 + blockIdx.x*256 + threadIdx.x;
    const bool valid = (p < p1);
    const int pc = valid ? p : (p1 - 1);
    const int e  = permr[pc];
    const int pd = invd[e];
    const int src = srcv[e], dst = dstv[e];

    // x rows to registers (independent random gathers, issued early)
    float xsr[S];
#pragma unroll
    for (int i = 0; i < S; i += 4) {
        float4 f = *(const float4*)(xs1 + (size_t)src*S + i);
        xsr[i] = f.x; xsr[i+1] = f.y; xsr[i+2] = f.z; xsr[i+3] = f.w;
    }
    float xvr[(V > 0) ? 48 : 4];
    if constexpr (V > 0) {
#pragma unroll
        for (int i = 0; i < 48; i += 4) {
            float4 f = *(const float4*)(xv1 + (size_t)src*48 + i);
            xvr[i] = f.x; xvr[i+1] = f.y; xvr[i+2] = f.z; xvr[i+3] = f.w;
        }
    }

    float es0, es1, es2, es3, ev0, ev1, ev2, tf;
    {
        float vx = pos[3*src+0] - pos[3*dst+0];
        float vy = pos[3*src+1] - pos[3*dst+1];
        float vz = pos[3*src+2] - pos[3*dst+2];
        float r  = sqrtf(vx*vx + vy*vy + vz*vz + 1e-12f);
        float ir = 1.0f/r;
        float uu = 2.0f*(r*(1.0f/3.5f) - 1.0f);
        float cut = (uu > 0.0f) ? 0.0f
                  : ((uu < -1.0f) ? 1.0f : 0.5f*(1.0f - cosf(PIF*uu)));
        es0 = ea[3*e+0]; es1 = ea[3*e+1]; es2 = ea[3*e+2]; es3 = cut;
        float cs = cut*SQ3F*ir;
        ev0 = cs*vx; ev1 = cs*vy; ev2 = cs*vz;
        tf = r*((float)(TT-1)/RMAXT);
    }
    float live = 1.f;
    int i0 = (int)tf;
    if (i0 > TT-2) { i0 = TT-2; live = 0.f; }   // w==0 beyond table range
    const float fr = tf - (float)i0;
    const float* te = TAB + (size_t)i0*(NG*8);
    float* msgrow = msg + (size_t)(pd - p0)*WM;

    if constexpr (NF > 1) __syncthreads();

    float tw[16], mv0[16], mv1[16], mv2[16];
    if constexpr (VEC_OUT) {
#pragma unroll
        for (int w = 0; w < 16; ++w) tw[w] = 0.f;
    }
    float fold8[8];
    if constexpr (FOLD) {
#pragma unroll
        for (int j = 0; j < 8; ++j) fold8[j] = 0.f;
    }

#pragma unroll
    for (int g = 0; g < NG; ++g) {
        const int j0 = 4*g;
        const float4 w0 = *(const float4*)(te + g*8);
        const float4 w1 = *(const float4*)(te + g*8 + 4);
        const float a0 = live*fmaf(fr, w1.x - w0.x, w0.x);
        const float a1 = live*fmaf(fr, w1.y - w0.y, w0.y);
        const float a2 = live*fmaf(fr, w1.z - w0.z, w0.z);
        const float a3 = live*fmaf(fr, w1.w - w0.w, w0.w);
        if (j0 < O1) {                                   // w1: scalar message
            const int u = g;
            float dv = a0*es0 + a1*es1 + a2*es2 + a3*es3;
            float v = 0.5f*xsr[u]*dv;
            if constexpr (FOLD) {
#pragma unroll
                for (int jj = 0; jj < 8; jj += 4) {
                    float4 wf = *(const float4*)&lWF[u*8 + jj];
                    fold8[jj+0] += v*wf.x; fold8[jj+1] += v*wf.y;
                    fold8[jj+2] += v*wf.z; fold8[jj+3] += v*wf.w;
                }
            } else {
                if (valid) msgrow[u] = v;
            }
        } else if (VEC_OUT && j0 < O2) {                 // w2: s->v, fold lin2_v
            const int u0 = j0 - O1;
            float m0 = xsr[u0+0]*a0, m1 = xsr[u0+1]*a1, m2 = xsr[u0+2]*a2, m3 = xsr[u0+3]*a3;
#pragma unroll
            for (int wq = 0; wq < 4; ++wq) {
                float4 f0 = *(const float4*)&lWF[(u0+0)*16 + 4*wq];
                float4 f1 = *(const float4*)&lWF[(u0+1)*16 + 4*wq];
                float4 f2 = *(const float4*)&lWF[(u0+2)*16 + 4*wq];
                float4 f3 = *(const float4*)&lWF[(u0+3)*16 + 4*wq];
                tw[4*wq+0] += m0*f0.x + m1*f1.x + m2*f2.x + m3*f3.x;
                tw[4*wq+1] += m0*f0.y + m1*f1.y + m2*f2.y + m3*f3.y;
                tw[4*wq+2] += m0*f0.z + m1*f1.z + m2*f2.z + m3*f3.z;
                tw[4*wq+3] += m0*f0.w + m1*f1.w + m2*f2.w + m3*f3.w;
            }
            if (j0 + 4 == O2) {
#pragma unroll
                for (int w = 0; w < 16; ++w) {
                    mv0[w] = tw[w]*ev0; mv1[w] = tw[w]*ev1; mv2[w] = tw[w]*ev2;
                }
            }
        } else if (VEC_OUT && V > 0 && j0 < O3) {        // w3: v->v, fold lin2_v
            const int u2 = (j0 - O2) >> 2;
            float dv = 0.5f*(a0*es0 + a1*es1 + a2*es2 + a3*es3);
            float q0 = dv*xvr[u2*3+0], q1 = dv*xvr[u2*3+1], q2 = dv*xvr[u2*3+2];
#pragma unroll
            for (int wq = 0; wq < 4; ++wq) {
                float4 wf = *(const float4*)&lWF[(S+u2)*16 + 4*wq];
                mv0[4*wq+0] += q0*wf.x; mv0[4*wq+1] += q0*wf.y; mv0[4*wq+2] += q0*wf.z; mv0[4*wq+3] += q0*wf.w;
                mv1[4*wq+0] += q1*wf.x; mv1[4*wq+1] += q1*wf.y; mv1[4*wq+2] += q1*wf.z; mv1[4*wq+3] += q1*wf.w;
                mv2[4*wq+0] += q2*wf.x; mv2[4*wq+1] += q2*wf.y; mv2[4*wq+2] += q2*wf.z; mv2[4*wq+3] += q2*wf.w;
            }
        } else if (V > 0) {                              // w4: v->s
            const int u0 = j0 - O3;
            float d0 = xvr[(u0+0)*3]*ev0 + xvr[(u0+0)*3+1]*ev1 + xvr[(u0+0)*3+2]*ev2;
            float d1 = xvr[(u0+1)*3]*ev0 + xvr[(u0+1)*3+1]*ev1 + xvr[(u0+1)*3+2]*ev2;
            float d2 = xvr[(u0+2)*3]*ev0 + xvr[(u0+2)*3+1]*ev1 + xvr[(u0+2)*3+2]*ev2;
            float d3 = xvr[(u0+3)*3]*ev0 + xvr[(u0+3)*3+1]*ev1 + xvr[(u0+3)*3+2]*ev2;
            float v0 = a0*d0*ISQ3, v1 = a1*d1*ISQ3, v2 = a2*d2*ISQ3, v3 = a3*d3*ISQ3;
            if constexpr (FOLD) {
#pragma unroll
                for (int jj = 0; jj < 8; jj += 4) {
                    float4 f0 = *(const float4*)&lWF[(S+u0+0)*8 + jj];
                    float4 f1 = *(const float4*)&lWF[(S+u0+1)*8 + jj];
                    float4 f2 = *(const float4*)&lWF[(S+u0+2)*8 + jj];
                    float4 f3 = *(const float4*)&lWF[(S+u0+3)*8 + jj];
                    fold8[jj+0] += v0*f0.x + v1*f1.x + v2*f2.x + v3*f3.x;
                    fold8[jj+1] += v0*f0.y + v1*f1.y + v2*f2.y + v3*f3.y;
                    fold8[jj+2] += v0*f0.z + v1*f1.z + v2*f2.z + v3*f3.z;
                    fold8[jj+3] += v0*f0.w + v1*f1.w + v2*f2.w + v3*f3.w;
                }
            } else {
                if (valid) {
                    msgrow[S+u0+0] = v0; msgrow[S+u0+1] = v1;
                    msgrow[S+u0+2] = v2; msgrow[S+u0+3] = v3;
                }
            }
        }
    }
    if constexpr (FOLD) {
        if (valid) {
            float4 f0 = {fold8[0], fold8[1], fold8[2], fold8[3]};
            float4 f1 = {fold8[4], fold8[5], fold8[6], fold8[7]};
            *(float4*)(msgrow + 0) = f0;
            *(float4*)(msgrow + 4) = f1;
        }
    } else if constexpr (VEC_OUT) {
        if (valid) {
#pragma unroll
            for (int w = 0; w < 16; w += 4) {
                float4 f0 = {mv0[w], mv0[w+1], mv0[w+2], mv0[w+3]};
                float4 f1 = {mv1[w], mv1[w+1], mv1[w+2], mv1[w+3]};
                float4 f2 = {mv2[w], mv2[w+1], mv2[w+2], mv2[w+3]};
                *(float4*)(msgrow + WMS + 0*16 + w) = f0;
                *(float4*)(msgrow + WMS + 1*16 + w) = f1;
                *(float4*)(msgrow + WMS + 2*16 + w) = f2;
            }
        }
    }
}

// ---------------------------------------------------------------- segmented sum
template<int W>
__global__ void k_segsum(const float* __restrict__ msg, float* __restrict__ Y,
                         const int* __restrict__ start, int p0, int p1, int first)
{
    int idx = blockIdx.x*blockDim.x + threadIdx.x;
    if (idx >= NN*W) return;
    int n = idx / W;
    int c = idx - n*W;
    int lo = start[n], hi = start[n+1];
    if (lo < p0) lo = p0;
    if (hi > p1) hi = p1;
    float s = 0.f;
    if (lo < hi) {
        const float* q = msg + (size_t)(lo - p0)*W + c;
        for (int p = lo; p < hi; ++p) { s += *q; q += W; }
    }
    if (first) Y[idx] = s;
    else if (lo < hi) Y[idx] += s;
}

// ---------------------------------------------------------------- node post + gate (in-place)
template<int SIN, int YSW, int WST, bool HASV>
__global__ void k_post(float* __restrict__ xsv, float* __restrict__ xvv,
                       const float* __restrict__ Y,
                       const float* __restrict__ scs, const float* __restrict__ scv,
                       const float* __restrict__ l2s,
                       float s_sc, float s_l2s, float s_scv, float s_l2v)
{
    __shared__ float Lscs[SIN*48];
    __shared__ float Ll2s[YSW*48];
    __shared__ float Lscv[HASV ? 256 : 1];
    for (int i = threadIdx.x; i < SIN*48; i += blockDim.x) Lscs[i] = scs[i];
    for (int i = threadIdx.x; i < YSW*48; i += blockDim.x) Ll2s[i] = l2s[i];
    if constexpr (HASV)
        for (int i = threadIdx.x; i < 256; i += blockDim.x) Lscv[i] = scv[i];
    __syncthreads();
    int n = blockIdx.x*blockDim.x + threadIdx.x;
    if (n >= NN) return;
    const float* yrow = Y + (size_t)n*WST;
    float xr[SIN];
#pragma unroll
    for (int u = 0; u < SIN; ++u) xr[u] = xsv[n*48 + u];
    float yr[YSW];
#pragma unroll
    for (int t = 0; t < YSW; ++t) yr[t] = yrow[t]*ISNN;
    float os[48];
    const float A = C_S*s_sc, B = C_X*s_l2s;
#pragma unroll
    for (int j = 0; j < 48; ++j) {
        float a = 0.f, b = 0.f;
#pragma unroll
        for (int u = 0; u < SIN; ++u) a += xr[u]*Lscs[u*48 + j];
#pragma unroll
        for (int t = 0; t < YSW; ++t) b += yr[t]*Ll2s[t*48 + j];
        os[j] = A*a + B*b;
    }
#pragma unroll
    for (int u = 0; u < 32; ++u) xsv[n*48 + u] = siluf(os[u]);
    float gg[16];
#pragma unroll
    for (int t = 0; t < 16; ++t) gg[t] = sigmf(os[32 + t]);
    const float sc3 = ISNN*s_l2v*(HASV ? C_X : 1.0f);
    if constexpr (HASV) {
        float vr[48];
#pragma unroll
        for (int i = 0; i < 48; ++i) vr[i] = xvv[n*48 + i];
        const float Av = C_S*s_scv;
#pragma unroll
        for (int w = 0; w < 16; ++w) {
            float s0 = 0.f, s1 = 0.f, s2 = 0.f;
#pragma unroll
            for (int v = 0; v < 16; ++v) {
                float wt = Lscv[v*16 + w];
                s0 += vr[v*3+0]*wt; s1 += vr[v*3+1]*wt; s2 += vr[v*3+2]*wt;
            }
            xvv[n*48 + w*3 + 0] = (Av*s0 + sc3*yrow[YSW + 0*16 + w])*gg[w];
            xvv[n*48 + w*3 + 1] = (Av*s1 + sc3*yrow[YSW + 1*16 + w])*gg[w];
            xvv[n*48 + w*3 + 2] = (Av*s2 + sc3*yrow[YSW + 2*16 + w])*gg[w];
        }
    } else {
#pragma unroll
        for (int w = 0; w < 16; ++w) {
            xvv[n*48 + w*3 + 0] = sc3*yrow[YSW + 0*16 + w]*gg[w];
            xvv[n*48 + w*3 + 1] = sc3*yrow[YSW + 1*16 + w]*gg[w];
            xvv[n*48 + w*3 + 2] = sc3*yrow[YSW + 2*16 + w]*gg[w];
        }
    }
}

// ---------------------------------------------------------------- layer4 post + head
__global__ void k_final(const float* __restrict__ xsv, const float* __restrict__ Y8,
                        const float* __restrict__ scs,
                        const float* __restrict__ Wh, const float* __restrict__ bh,
                        float* __restrict__ out)
{
    __shared__ float Lscs[32*8];
    __shared__ float Lwh[24];
    __shared__ float Lbh[3];
    for (int i = threadIdx.x; i < 32*8; i += blockDim.x) Lscs[i] = scs[i];
    if (threadIdx.x < 24) Lwh[threadIdx.x] = Wh[threadIdx.x];
    if (threadIdx.x < 3)  Lbh[threadIdx.x] = bh[threadIdx.x];
    __syncthreads();
    int n = blockIdx.x*blockDim.x + threadIdx.x;
    if (n >= NN) return;
    float xr[32];
#pragma unroll
    for (int u = 0; u < 32; ++u) xr[u] = xsv[n*48 + u];
    const float CB = C_X*RS48*ISNN;
    float s8[8];
#pragma unroll
    for (int j = 0; j < 8; ++j) {
        float a = 0.f;
#pragma unroll
        for (int u = 0; u < 32; ++u) a += xr[u]*Lscs[u*8 + j];
        s8[j] = C_S*RS32*a + CB*Y8[n*8 + j];
    }
#pragma unroll
    for (int c = 0; c < 3; ++c) {
        float o = Lbh[c];
#pragma unroll
        for (int j = 0; j < 8; ++j) o += s8[j]*Lwh[j*3 + c];
        out[n*3 + c] = o;
    }
}

// ---------------------------------------------------------------- launcher
extern "C" void kernel_launch(void* const* d_in, const int* in_sizes, int n_in,
                              void* d_out, int out_size, void* d_ws, size_t ws_size,
                              hipStream_t stream)
{
    const float* pos       = (const float*)d_in[0];
    const float* onehot    = (const float*)d_in[1];
    const float* eattr     = (const float*)d_in[2];
    const float* W_embed   = (const float*)d_in[3];
    const float* b_embed   = (const float*)d_in[4];
    const float* l1_lin1_s = (const float*)d_in[5];
    const float* l1_sc_s   = (const float*)d_in[6];
    const float* l1_R1     = (const float*)d_in[7];
    const float* l1_R2     = (const float*)d_in[8];
    const float* l1_lin2_s = (const float*)d_in[9];
    const float* l1_lin2_v = (const float*)d_in[10];
    const float* l2_lin1_s = (const float*)d_in[11];
    const float* l2_lin1_v = (const float*)d_in[12];
    const float* l2_sc_s   = (const float*)d_in[13];
    const float* l2_sc_v   = (const float*)d_in[14];
    const float* l2_R1     = (const float*)d_in[15];
    const float* l2_R2     = (const float*)d_in[16];
    const float* l2_lin2_s = (const float*)d_in[17];
    const float* l2_lin2_v = (const float*)d_in[18];
    const float* l3_lin1_s = (const float*)d_in[19];
    const float* l3_lin1_v = (const float*)d_in[20];
    const float* l3_sc_s   = (const float*)d_in[21];
    const float* l3_sc_v   = (const float*)d_in[22];
    const float* l3_R1     = (const float*)d_in[23];
    const float* l3_R2     = (const float*)d_in[24];
    const float* l3_lin2_s = (const float*)d_in[25];
    const float* l3_lin2_v = (const float*)d_in[26];
    const float* l4_lin1_s = (const float*)d_in[27];
    const float* l4_lin1_v = (const float*)d_in[28];
    const float* l4_sc_s   = (const float*)d_in[29];
    const float* l4_R1     = (const float*)d_in[30];
    const float* l4_R2     = (const float*)d_in[31];
    const float* l4_lin2_s = (const float*)d_in[32];
    const float* W_head    = (const float*)d_in[33];
    const float* b_head    = (const float*)d_in[34];
    const int*   eidx      = (const int*)d_in[35];
    const int* srcv = eidx;
    const int* dstv = eidx + NE;

    float* ws = (float*)d_ws;
    size_t off = 0;
    float* XS     = ws + off; off += 48ull*NN;
    float* XV     = ws + off; off += 48ull*NN;
    float* XS1    = ws + off; off += 32ull*NN;
    float* XV1    = ws + off; off += 48ull*NN;
    float* Y      = ws + off; off += 96ull*NN;
    float* TAB    = ws + off; off += (size_t)TT*60*8;
    int*   start  = (int*)(ws + off); off += ((NN + 1 + 3) & ~3);
    int*   cursor = (int*)(ws + off); off += NN;
    int*   cursR  = (int*)(ws + off); off += 32768;
    int*   permD  = (int*)(ws + off); off += NE;
    int*   invd   = (int*)(ws + off); off += NE;
    int*   permR  = (int*)(ws + off); off += NE;
    float* MSG    = ws + off;
    size_t totalFloats = ws_size/4;
    size_t msgCap = (totalFloats > off) ? (totalFloats - off) : 0;

    dim3 th(256), be((NE + 255)/256), bn((NN + 255)/256);

    // chunk size (shared by all layers; key = (dstpos/EC, rbucket))
    long ECall;
    {
        long cap = (long)(msgCap/96) & ~255L;
        ECall = (cap >= NE) ? NE : cap;
        if (ECall < 51200) ECall = 51200;   // cap bins at 16*NBR
    }
    int nchunk = (int)((NE + ECall - 1)/ECall);
    int nbinsR = nchunk*NBR;

    // ---- dst sort + inverse
    hipMemsetAsync(cursor, 0, NN*sizeof(int), stream);
    k_hist<<<be, th, 0, stream>>>(dstv, cursor);
    k_scan<<<1, 1024, 0, stream>>>(cursor, start);
    k_scatter<<<be, th, 0, stream>>>(dstv, cursor, permD, invd);
    // ---- r sort (chunk-compound key)
    hipMemsetAsync(cursR, 0, nbinsR*sizeof(int), stream);
    k_histr<<<be, th, 0, stream>>>(pos, srcv, dstv, invd, cursR, (int)ECall);
    k_scanN<<<1, 1024, 0, stream>>>(cursR, nbinsR);
    k_scatr<<<be, th, 0, stream>>>(pos, srcv, dstv, invd, cursR, permR, (int)ECall);

    k_embed<<<(NN*64 + 255)/256, th, 0, stream>>>(onehot, W_embed, b_embed, XS);

    dim3 tb(512), gb(TT/8);

    // ---- layer 1 (S=16, V=0, WOUT=80; W = 16 + 48 = 64)
    {
        k_pre<16,16,0><<<bn, th, 0, stream>>>(XS, nullptr, l1_lin1_s, nullptr, XS1, XV1, RS16, RS16);
        k_tab<80><<<gb, tb, 0, stream>>>(l1_R1, l1_R2, TAB);
        for (long c0 = 0; c0 < NE; c0 += ECall) {
            int p0 = (int)c0, p1 = (int)((c0 + ECall < NE) ? c0 + ECall : NE);
            dim3 ge(((p1-p0) + 255)/256);
            k_edge5<16,0,80,true,false,64,16><<<ge, th, 0, stream>>>(
                pos, eattr, srcv, dstv, permR, invd, XS1, XV1, TAB, l1_lin2_v, MSG, p0, p1);
            dim3 gs((NN*64 + 255)/256);
            k_segsum<64><<<gs, th, 0, stream>>>(MSG, Y, start, p0, p1, c0 == 0);
        }
        k_post<16,16,64,false><<<bn, th, 0, stream>>>(XS, XV, Y, l1_sc_s, nullptr, l1_lin2_s,
                                                      RS16, RS16, 0.f, RS16);
    }

    // ---- layers 2,3 (S=32, V=16, WOUT=240; W = 48 + 48 = 96)
    const float* L2w[2][6] = {
        {l2_lin1_s, l2_lin1_v, l2_R1, l2_R2, l2_lin2_v, l2_lin2_s},
        {l3_lin1_s, l3_lin1_v, l3_R1, l3_R2, l3_lin2_v, l3_lin2_s}};
    const float* L2sc[2][2] = {{l2_sc_s, l2_sc_v}, {l3_sc_s, l3_sc_v}};
    for (int L = 0; L < 2; ++L) {
        k_pre<32,32,16><<<bn, th, 0, stream>>>(XS, XV, L2w[L][0], L2w[L][1], XS1, XV1, RS32, RS16);
        k_tab<240><<<gb, tb, 0, stream>>>(L2w[L][2], L2w[L][3], TAB);
        for (long c0 = 0; c0 < NE; c0 += ECall) {
            int p0 = (int)c0, p1 = (int)((c0 + ECall < NE) ? c0 + ECall : NE);
            dim3 ge(((p1-p0) + 255)/256);
            k_edge5<32,16,240,true,false,96,48><<<ge, th, 0, stream>>>(
                pos, eattr, srcv, dstv, permR, invd, XS1, XV1, TAB, L2w[L][4], MSG, p0, p1);
            dim3 gs((NN*96 + 255)/256);
            k_segsum<96><<<gs, th, 0, stream>>>(MSG, Y, start, p0, p1, c0 == 0);
        }
        k_post<32,48,96,true><<<bn, th, 0, stream>>>(XS, XV, Y, L2sc[L][0], L2sc[L][1], L2w[L][5],
                                                     RS32, RS48, RS16, RS48);
    }

    // ---- layer 4 (S=32, V=16, WOUT=144; lin2_s folded -> W = 8)
    {
        k_pre<32,32,16><<<bn, th, 0, stream>>>(XS, XV, l4_lin1_s, l4_lin1_v, XS1, XV1, RS32, RS16);
        k_tab<144><<<gb, tb, 0, stream>>>(l4_R1, l4_R2, TAB);
        for (long c0 = 0; c0 < NE; c0 += ECall) {
            int p0 = (int)c0, p1 = (int)((c0 + ECall < NE) ? c0 + ECall : NE);
            dim3 ge(((p1-p0) + 255)/256);
            k_edge5<32,16,144,false,true,8,48><<<ge, th, 0, stream>>>(
                pos, eattr, srcv, dstv, permR, invd, XS1, XV1, TAB, l4_lin2_s, MSG, p0, p1);
            dim3 gs((NN*8 + 255)/256);
            k_segsum<8><<<gs, th, 0, stream>>>(MSG, Y, start, p0, p1, c0 == 0);
        }
        k_final<<<bn, th, 0, stream>>>(XS, Y, l4_sc_s, W_head, b_head, (float*)d_out);
    }
}